// Round 19
// baseline (13219.998 us; speedup 1.0000x reference)
//
#include <hip/hip_runtime.h>
#include <hip/hip_bf16.h>

using bf16x8 = __attribute__((ext_vector_type(8))) short;  // 8 bf16, 4 VGPRs
using f32x4  = __attribute__((ext_vector_type(4))) float;

static constexpr int NB = 64, NT = 256, NE = 1024, NH = 1024, NL = 3;
static constexpr int NR = 4096, KC = 2048;
static constexpr int STATE = NL * NB * NH;             // 196608
static constexpr int BH = NB * NH;                     // 65536 (one panel)
static constexpr size_t WCAT_E = (size_t)NL * NR * KC;  // 25,165,824 bf16
static constexpr size_t XBF_E  = (size_t)NT * NB * NE;  // 16,777,216 bf16
static constexpr size_t HSEQ_E = (size_t)(NT + 1) * STATE;  // 50,528,256 bf16
static constexpr size_t GP_E   = 3u * 4 * 64 * 4 * 4 * 256; // 3,145,728 f32
static constexpr int FSTR  = 32;                       // u32s per flag slot (128B)
static constexpr int NFLAG = 256 * FSTR;
static constexpr int NREL  = 32 * FSTR;
static constexpr size_t FLAGS_W = NFLAG + NREL;
static constexpr int PSTR = 18;                        // fallback LDS pad
static constexpr size_t PART_BYTES = 3u * 8 * 4 * 16 * PSTR * 4;

// Fragment-tiled panel layout (64 m x 1024 k bf16 = 32x4 tiles of 1KB):
__host__ __device__ __forceinline__ size_t off_e(int m, int k) {
    return ((size_t)((m >> 4) * 32 + (k >> 5))) * 512 +
           (((k >> 3) & 3) * 16 + (m & 15)) * 8 + (k & 7);
}

// ---------------- prologue kernels ----------------

// K-split W layout: [l][ng(64)][g(4)][kt(64)][lane(64)][e(8)]
//   r = g*1024 + ng*16 + (lane&15); k = kt*32 + (lane>>4)*8 + e
__global__ void __launch_bounds__(256)
convert_w_ks(const float* __restrict__ wih, const float* __restrict__ whh,
             __hip_bfloat16* __restrict__ wt) {
    size_t i = (size_t)blockIdx.x * 256 + threadIdx.x;
    const size_t stride = (size_t)gridDim.x * 256;
    for (; i < WCAT_E; i += stride) {
        const int e    = (int)(i & 7);
        const int lane = (int)((i >> 3) & 63);
        const int kt   = (int)((i >> 9) & 63);
        const int g    = (int)((i >> 15) & 3);
        const int ng   = (int)((i >> 17) & 63);
        const int l    = (int)(i >> 23);
        const int r    = g * 1024 + ng * 16 + (lane & 15);
        const int k    = kt * 32 + (lane >> 4) * 8 + e;
        const float v = (k < NE) ? wih[((size_t)l * NR + r) * NE + k]
                                 : whh[((size_t)l * NR + r) * NH + (k - NE)];
        wt[i] = __float2bfloat16(v);
    }
}

// fallback (R16/R18) W layout
__global__ void __launch_bounds__(256)
convert_w_r16(const float* __restrict__ wih, const float* __restrict__ whh,
              __hip_bfloat16* __restrict__ wcat) {
    size_t i = (size_t)blockIdx.x * 256 + threadIdx.x;
    const size_t stride = (size_t)gridDim.x * 256;
    for (; i < WCAT_E; i += stride) {
        const int e    = (int)(i & 7);
        const int lane = (int)((i >> 3) & 63);
        const int kt   = (int)((i >> 9) & 63);
        const int ug   = (int)((i >> 15) & 255);
        const int l    = (int)(i >> 23);
        const int nfr  = lane & 15, kg = lane >> 4;
        const int r    = (nfr >> 2) * 1024 + ug * 4 + (nfr & 3);
        const int k    = kt * 32 + kg * 8 + e;
        const float v = (k < NE) ? wih[((size_t)l * NR + r) * NE + k]
                                 : whh[((size_t)l * NR + r) * NH + (k - NE)];
        wcat[i] = __float2bfloat16(v);
    }
}

__global__ void __launch_bounds__(256)
convert_x(const float* __restrict__ x, __hip_bfloat16* __restrict__ xbf) {
    size_t i = (size_t)blockIdx.x * 256 + threadIdx.x;
    const size_t stride = (size_t)gridDim.x * 256;
    for (; i < XBF_E; i += stride) {
        const int e = (int)(i & (NE - 1));
        const int m = (int)((i >> 10) & 63);
        const int t = (int)(i >> 16);
        xbf[(size_t)t * BH + off_e(m, e)] =
            __float2bfloat16(x[((size_t)m * NT + t) * NE + e]);
    }
}

__global__ void __launch_bounds__(256)
init_h(const float* __restrict__ enc, __hip_bfloat16* __restrict__ h0,
       unsigned* __restrict__ flags) {
    const int i = blockIdx.x * 256 + threadIdx.x;
    if (i < STATE) {
        const int u = i & 1023, m = (i >> 10) & 63, l = i >> 16;
        h0[(size_t)l * BH + off_e(m, u)] = __float2bfloat16(enc[m * NH + u]);
    }
    if (i < (int)FLAGS_W) flags[i] = 0u;
}

// ---------------- helpers ----------------

__device__ __forceinline__ unsigned short bf16bits(float f) {
    const __hip_bfloat16 h = __float2bfloat16(f);
    union { __hip_bfloat16 h; unsigned short s; } u{h};
    return u.s;
}

__device__ __forceinline__ void grid_barrier(unsigned* __restrict__ flags,
                                             unsigned* __restrict__ release,
                                             int bid, int tid, unsigned gen) {
    asm volatile("s_waitcnt vmcnt(0)" ::: "memory");
    __syncthreads();
    if (tid == 0)
        __hip_atomic_store(&flags[bid * FSTR], gen,
                           __ATOMIC_RELAXED, __HIP_MEMORY_SCOPE_AGENT);
    const int lane = tid & 63, w = tid >> 6;
    if (bid == 0) {
        if (tid < 256) {
            for (;;) {
                const unsigned v = __hip_atomic_load(&flags[tid * FSTR],
                                      __ATOMIC_RELAXED, __HIP_MEMORY_SCOPE_AGENT);
                if (__all((int)(v >= gen))) break;
                __builtin_amdgcn_s_sleep(2);
            }
        }
        __syncthreads();
        if (w < 4 && lane < 8)
            __hip_atomic_store(&release[(w * 8 + lane) * FSTR], gen,
                               __ATOMIC_RELAXED, __HIP_MEMORY_SCOPE_AGENT);
    } else {
        if (tid < 64) {
            for (;;) {
                const unsigned v = __hip_atomic_load(&release[(bid >> 3) * FSTR],
                                      __ATOMIC_RELAXED, __HIP_MEMORY_SCOPE_AGENT);
                if (v >= gen) break;
                __builtin_amdgcn_s_sleep(2);
            }
        }
        __syncthreads();
    }
}

#define LOAD8S(dst, base)                                         \
    _Pragma("unroll")                                             \
    for (int kb = 0; kb < 8; ++kb)                                \
        dst[kb] = *(const bf16x8*)((base) + kb * 512);

#define MFMA8(accv, asrc, bsrc)                                   \
    _Pragma("unroll")                                             \
    for (int kb = 0; kb < 8; ++kb)                                \
        accv = __builtin_amdgcn_mfma_f32_16x16x32_bf16(           \
            asrc[kb], bsrc[kb], accv, 0, 0, 0);

#define SB __builtin_amdgcn_sched_barrier(0)

__device__ __forceinline__ int gpidx(int l, int kss, int ng, int g, int mt) {
    return ((((l * 4 + kss) * 64 + ng) * 4 + g) * 4 + mt) * 256;
}

// ================= K-split kernel (grid 256 = 64 ng x 4 ks) ===============
// Block (ng, ks): 64 gate rows (16 units x 4 gates) x 512-k slice.
// Per-step L2 reads 384KB/block (vs 960). Partials exchanged via sc1 gpart;
// cell phase (m-slab = ks) sums 4 K-slices after barrier 1. 2 barriers/step.
__global__ void __launch_bounds__(512, 2)
lstm_ks(const float* __restrict__ bias,
        const __hip_bfloat16* __restrict__ wt,
        const __hip_bfloat16* __restrict__ xbf,
        __hip_bfloat16* __restrict__ hseq,
        float* __restrict__ gpart,
        float* __restrict__ out,
        unsigned* __restrict__ flags)
{
    const int tid  = threadIdx.x;
    const int lane = tid & 63;
    const int wv   = tid >> 6;
    const int bid  = blockIdx.x;
    const int ng   = bid & 63;            // unit group (16 units)
    const int ks   = bid >> 6;            // k-slice 0..3
    const int mt   = wv & 3;              // wave's m-tile
    const int gp   = wv >> 2;             // wave's gate pair
    const int g0   = gp * 2, g1 = g0 + 1;
    const int nfr  = lane & 15;
    const int mgrp = (lane >> 4) * 4;
    const size_t lane8 = (size_t)lane * 8;
    const int kb0  = (ks < 2 ? ks : ks - 2) * 16;   // A k-block origin

    float* hT   = out;
    float* cT   = out + STATE;
    float* outs = out + 2 * STATE;
    unsigned* release = flags + NFLAG;

    float c0 = 0.f, c1 = 0.f, c2 = 0.f;
    unsigned gen = 1;

#define WBASE(l, g, h) (wt + ((((size_t)(l) * 64 + ng) * 4 + (g)) * 64 +     \
                              ks * 16 + (h) * 8) * 512 + lane8)
#define ABASE(pan, h)  ((pan) + (size_t)(mt * 32 + kb0 + (h) * 8) * 512 + lane8)

#define STOREP_KS(l, accA, accB)                                             \
    {                                                                        \
        float* pb0 = gpart + gpidx(l, ks, ng, g0, mt) + nfr;                 \
        float* pb1 = gpart + gpidx(l, ks, ng, g1, mt) + nfr;                 \
        _Pragma("unroll")                                                    \
        for (int j = 0; j < 4; ++j) {                                        \
            __hip_atomic_store(pb0 + (mgrp + j) * 16, accA[j],               \
                __ATOMIC_RELAXED, __HIP_MEMORY_SCOPE_AGENT);                 \
            __hip_atomic_store(pb1 + (mgrp + j) * 16, accB[j],               \
                __ATOMIC_RELAXED, __HIP_MEMORY_SCOPE_AGENT);                 \
        }                                                                    \
    }

    for (int s = 0; s < NT + 2; ++s) {
        const int t0 = (s < NT) ? s : NT - 1;
        const int t1c = (s - 1 < 0) ? 0 : ((s - 1 < NT) ? s - 1 : NT - 1);
        const int t2c = (s - 2 < 0) ? 0 : ((s - 2 < NT) ? s - 2 : NT - 1);

        // A panels: ks<2 -> layer input slice; ks>=2 -> h(l, t-1) slice
        const __hip_bfloat16* aL0 = (ks < 2)
            ? xbf + (size_t)t0 * BH
            : hseq + (size_t)t0 * STATE;
        const __hip_bfloat16* aL1 = (ks < 2)
            ? hseq + (size_t)(t1c + 1) * STATE
            : hseq + (size_t)t1c * STATE + BH;
        const __hip_bfloat16* aL2 = (ks < 2)
            ? hseq + (size_t)(t2c + 1) * STATE + BH
            : hseq + (size_t)t2c * STATE + 2 * BH;

        bf16x8 a0[8], a1[8], w0[8], w1[8], w2[8], w3[8];
        f32x4 p0, p1;

        // ---- phase 1: 12 MFMA clusters, loads 4 clusters ahead ----
        LOAD8S(a0, ABASE(aL0, 0)); LOAD8S(a1, ABASE(aL0, 1));
        LOAD8S(w0, WBASE(0, g0, 0)); LOAD8S(w1, WBASE(0, g0, 1));
        LOAD8S(w2, WBASE(0, g1, 0)); LOAD8S(w3, WBASE(0, g1, 1)); SB;
        p0 = f32x4{0.f, 0.f, 0.f, 0.f}; p1 = f32x4{0.f, 0.f, 0.f, 0.f};
        MFMA8(p0, a0, w0); SB; LOAD8S(w0, WBASE(1, g0, 0)); SB;
        MFMA8(p0, a1, w1); SB; LOAD8S(w1, WBASE(1, g0, 1)); SB;
        MFMA8(p1, a0, w2); SB; LOAD8S(w2, WBASE(1, g1, 0));
                               LOAD8S(a0, ABASE(aL1, 0)); SB;
        MFMA8(p1, a1, w3); SB; LOAD8S(w3, WBASE(1, g1, 1));
                               LOAD8S(a1, ABASE(aL1, 1)); SB;
        STOREP_KS(0, p0, p1);
        p0 = f32x4{0.f, 0.f, 0.f, 0.f}; p1 = f32x4{0.f, 0.f, 0.f, 0.f};
        MFMA8(p0, a0, w0); SB; LOAD8S(w0, WBASE(2, g0, 0)); SB;
        MFMA8(p0, a1, w1); SB; LOAD8S(w1, WBASE(2, g0, 1)); SB;
        MFMA8(p1, a0, w2); SB; LOAD8S(w2, WBASE(2, g1, 0));
                               LOAD8S(a0, ABASE(aL2, 0)); SB;
        MFMA8(p1, a1, w3); SB; LOAD8S(w3, WBASE(2, g1, 1));
                               LOAD8S(a1, ABASE(aL2, 1)); SB;
        STOREP_KS(1, p0, p1);
        p0 = f32x4{0.f, 0.f, 0.f, 0.f}; p1 = f32x4{0.f, 0.f, 0.f, 0.f};
        MFMA8(p0, a0, w0); SB;
        MFMA8(p0, a1, w1); SB;
        MFMA8(p1, a0, w2); SB;
        MFMA8(p1, a1, w3); SB;
        STOREP_KS(2, p0, p1);

        grid_barrier(flags, release, bid, tid, gen++);   // partials visible

        // ---- phase 2: cell for m-slab ks, units of ng, 3 layers ----
        if (tid < 256) {
            const int cmi = tid >> 4, cu = tid & 15;
            const int cunit = ng * 16 + cu;
            const int cm = ks * 16 + cmi;
            #pragma unroll
            for (int l = 0; l < NL; ++l) {
                const int t = s - l;
                float gv[4];
                #pragma unroll
                for (int g = 0; g < 4; ++g) {
                    float sum = bias[l * NR + g * NH + cunit];
                    #pragma unroll
                    for (int kss = 0; kss < 4; ++kss)
                        sum += __hip_atomic_load(
                            gpart + gpidx(l, kss, ng, g, ks) + cmi * 16 + cu,
                            __ATOMIC_RELAXED, __HIP_MEMORY_SCOPE_AGENT);
                    gv[g] = sum;
                }
                if (t >= 0 && t < NT) {
                    float& cref = (l == 0) ? c0 : ((l == 1) ? c1 : c2);
                    const float iv = 1.f / (1.f + __expf(-gv[0]));
                    const float fv = 1.f / (1.f + __expf(-gv[1]));
                    const float gg = 1.f - 2.f / (__expf(2.f * gv[2]) + 1.f);
                    const float ov = 1.f / (1.f + __expf(-gv[3]));
                    const float cn = fv * cref + iv * gg;
                    const float hn = ov * (1.f - 2.f / (__expf(2.f * cn) + 1.f));
                    cref = cn;
                    __hip_atomic_store(
                        (unsigned short*)(hseq + (size_t)(t + 1) * STATE +
                                          l * BH + off_e(cm, cunit)),
                        bf16bits(hn),
                        __ATOMIC_RELAXED, __HIP_MEMORY_SCOPE_AGENT);
                    if (l == 2)
                        outs[((size_t)cm * NT + t) * NH + cunit] = hn;
                    if (t == NT - 1) {
                        hT[l * BH + cm * NH + cunit] = hn;
                        cT[l * BH + cm * NH + cunit] = cn;
                    }
                }
            }
        }
        grid_barrier(flags, release, bid, tid, gen++);   // h visible, WAR safe
    }
#undef WBASE
#undef ABASE
#undef STOREP_KS
}

// ================= fallback: R18 proven kernel ============================

#define ZEROACC                                                    \
    acc0 = f32x4{0.f, 0.f, 0.f, 0.f}; acc1 = f32x4{0.f, 0.f, 0.f, 0.f}; \
    acc2 = f32x4{0.f, 0.f, 0.f, 0.f}; acc3 = f32x4{0.f, 0.f, 0.f, 0.f};

__device__ __forceinline__ int pidx(int st, int w, int mt, int m, int n) {
    return (((st * 8 + w) * 4 + mt) * 16 + m) * PSTR + n;
}
#define STOREP(st)                                                 \
    _Pragma("unroll")                                              \
    for (int j = 0; j < 4; ++j) {                                  \
        part[pidx(st, wv, 0, mgrp + j, nfr)] = acc0[j];            \
        part[pidx(st, wv, 1, mgrp + j, nfr)] = acc1[j];            \
        part[pidx(st, wv, 2, mgrp + j, nfr)] = acc2[j];            \
        part[pidx(st, wv, 3, mgrp + j, nfr)] = acc3[j];            \
    }

__global__ void __launch_bounds__(512, 2)
lstm_pipe(const float* __restrict__ bias,
          const __hip_bfloat16* __restrict__ wcat,
          const __hip_bfloat16* __restrict__ xbf,
          __hip_bfloat16* __restrict__ hseq,
          float* __restrict__ out,
          unsigned* __restrict__ flags)
{
    extern __shared__ float part[];
    const int tid  = threadIdx.x;
    const int lane = tid & 63;
    const int wv   = tid >> 6;
    const int bid  = blockIdx.x;
    const int ug   = (bid & 7) * 32 + (bid >> 3);
    const int U0   = ug * 4;
    const int nfr  = lane & 15;
    const int mgrp = (lane >> 4) * 4;

    float* hT   = out;
    float* cT   = out + STATE;
    float* outs = out + 2 * STATE;
    unsigned* release = flags + NFLAG;

    const bool xpart = (wv < 4);
    const int  ksl   = xpart ? wv : (wv - 4);

    const __hip_bfloat16* wp0 = wcat + ((size_t)ug * 64 + wv * 8) * 512 + lane * 8;
    const __hip_bfloat16* wp1 = wp0 + (size_t)1 * NR * KC;
    const __hip_bfloat16* wp2 = wp0 + (size_t)2 * NR * KC;
    const size_t lane8 = (size_t)(ksl * 8) * 512 + lane * 8;

    float cA = 0.f, cB = 0.f;
    unsigned gen = 1;

    for (int s = 0; s < NT + 2; ++s) {
        const int t0 = (s < NT) ? s : NT - 1;
        const int t1c = (s - 1 < 0) ? 0 : ((s - 1 < NT) ? s - 1 : NT - 1);
        const int t2c = (s - 2 < 0) ? 0 : ((s - 2 < NT) ? s - 2 : NT - 1);

        const __hip_bfloat16* ap0 = xpart ? (xbf + (size_t)t0 * BH)
                                          : (hseq + (size_t)t0 * STATE);
        const __hip_bfloat16* ap1 = xpart ? (hseq + (size_t)(t1c + 1) * STATE)
                                          : (hseq + (size_t)t1c * STATE + BH);
        const __hip_bfloat16* ap2 = xpart ? (hseq + (size_t)(t2c + 1) * STATE + BH)
                                          : (hseq + (size_t)t2c * STATE + 2 * BH);
        const __hip_bfloat16* a00 = ap0 + lane8;
        const __hip_bfloat16* a10 = ap1 + lane8;
        const __hip_bfloat16* a20 = ap2 + lane8;

        bf16x8 bA[8], bB[8], aX[8], aY[8], aZ[8];
        f32x4 acc0, acc1, acc2, acc3;

        LOAD8S(bA, wp0);
        LOAD8S(aX, a00 + 0 * 32 * 512);
        LOAD8S(aY, a00 + 1 * 32 * 512);
        LOAD8S(aZ, a00 + 2 * 32 * 512);
        LOAD8S(bB, wp1);
        SB;
        ZEROACC;
        MFMA8(acc0, aX, bA); SB; LOAD8S(aX, a00 + 3 * 32 * 512); SB;
        MFMA8(acc1, aY, bA); SB; LOAD8S(aY, a10 + 0 * 32 * 512); SB;
        MFMA8(acc2, aZ, bA); SB; LOAD8S(aZ, a10 + 1 * 32 * 512); SB;
        MFMA8(acc3, aX, bA); SB; LOAD8S(aX, a10 + 2 * 32 * 512);
                                 LOAD8S(bA, wp2); SB;
        STOREP(0);
        ZEROACC;
        MFMA8(acc0, aY, bB); SB; LOAD8S(aY, a10 + 3 * 32 * 512); SB;
        MFMA8(acc1, aZ, bB); SB; LOAD8S(aZ, a20 + 0 * 32 * 512); SB;
        MFMA8(acc2, aX, bB); SB; LOAD8S(aX, a20 + 1 * 32 * 512); SB;
        MFMA8(acc3, aY, bB); SB; LOAD8S(aY, a20 + 2 * 32 * 512); SB;
        STOREP(1);
        ZEROACC;
        MFMA8(acc0, aZ, bA); SB; LOAD8S(aZ, a20 + 3 * 32 * 512); SB;
        MFMA8(acc1, aX, bA); SB;
        MFMA8(acc2, aY, bA); SB;
        MFMA8(acc3, aZ, bA); SB;
        STOREP(2);
        __syncthreads();

        if (tid < 384) {
            const int st = tid >> 7, r = tid & 127;
            const int t  = s - st;
            if (t >= 0 && t < NT) {
                const int cm = r >> 1, cp = (r & 1) * 2;
                const float* bias_l = bias + (size_t)st * NR;
                float hn2[2], cn2[2];
                #pragma unroll
                for (int j = 0; j < 2; ++j) {
                    const int ul = cp + j;
                    const int cunit = U0 + ul;
                    float gv[4];
                    #pragma unroll
                    for (int g = 0; g < 4; ++g) {
                        float ssum = bias_l[g * NH + cunit];
                        #pragma unroll
                        for (int w2 = 0; w2 < 8; ++w2)
                            ssum += part[pidx(st, w2, cm >> 4, cm & 15, g * 4 + ul)];
                        gv[g] = ssum;
                    }
                    const float iv = 1.f / (1.f + __expf(-gv[0]));
                    const float fv = 1.f / (1.f + __expf(-gv[1]));
                    const float gg = 1.f - 2.f / (__expf(2.f * gv[2]) + 1.f);
                    const float ov = 1.f / (1.f + __expf(-gv[3]));
                    float& cref = (j == 0) ? cA : cB;
                    const float cn = fv * cref + iv * gg;
                    const float hn = ov * (1.f - 2.f / (__expf(2.f * cn) + 1.f));
                    cref = cn;
                    hn2[j] = hn; cn2[j] = cn;
                }
                __hip_bfloat16* hw = hseq + (size_t)(t + 1) * STATE + st * BH;
                const int u = U0 + cp;
                const size_t off = ((size_t)((cm >> 4) * 32 + (u >> 5))) * 512 +
                                   (((u >> 3) & 3) * 16 + (cm & 15)) * 8 + (u & 7);
                const unsigned pk = (unsigned)bf16bits(hn2[0]) |
                                    ((unsigned)bf16bits(hn2[1]) << 16);
                __hip_atomic_store((unsigned*)(hw + off), pk,
                                   __ATOMIC_RELAXED, __HIP_MEMORY_SCOPE_AGENT);
                if (st == 2) {
                    outs[((size_t)cm * NT + t) * NH + u]     = hn2[0];
                    outs[((size_t)cm * NT + t) * NH + u + 1] = hn2[1];
                }
                if (t == NT - 1) {
                    float* hT_l = hT + st * BH;
                    float* cT_l = cT + st * BH;
                    hT_l[cm * NH + u]     = hn2[0];
                    hT_l[cm * NH + u + 1] = hn2[1];
                    cT_l[cm * NH + u]     = cn2[0];
                    cT_l[cm * NH + u + 1] = cn2[1];
                }
            }
        }
        if (s < NT + 1) grid_barrier(flags, release, bid, tid, gen++);
    }
}

// ---------------- launcher ----------------

extern "C" void kernel_launch(void* const* d_in, const int* in_sizes, int n_in,
                              void* d_out, int out_size, void* d_ws, size_t ws_size,
                              hipStream_t stream) {
    const float* inputs = (const float*)d_in[0];
    const float* enc    = (const float*)d_in[1];
    const float* W_ih   = (const float*)d_in[2];
    const float* W_hh   = (const float*)d_in[3];
    const float* bias   = (const float*)d_in[4];
    float* out = (float*)d_out;

    __hip_bfloat16* wcat  = (__hip_bfloat16*)d_ws;
    __hip_bfloat16* xbf   = wcat + WCAT_E;
    __hip_bfloat16* hseq  = xbf + XBF_E;
    unsigned*       flags = (unsigned*)(hseq + HSEQ_E);
    float*          gpart = (float*)(flags + FLAGS_W);

    const size_t need_ks = (WCAT_E + XBF_E + HSEQ_E) * 2 + FLAGS_W * 4 + GP_E * 4;

    convert_x<<<dim3(2048), dim3(256), 0, stream>>>(inputs, xbf);
    init_h<<<dim3(768), dim3(256), 0, stream>>>(enc, hseq, flags);

    if (ws_size >= need_ks) {
        convert_w_ks<<<dim3(4096), dim3(256), 0, stream>>>(W_ih, W_hh, wcat);
        lstm_ks<<<dim3(256), dim3(512), 0, stream>>>(
            bias, wcat, xbf, hseq, gpart, out, flags);
    } else {
        // proven R18 path (~185.0 MB of ws)
        (void)hipFuncSetAttribute((const void*)lstm_pipe,
                                  hipFuncAttributeMaxDynamicSharedMemorySize,
                                  (int)PART_BYTES);
        convert_w_r16<<<dim3(4096), dim3(256), 0, stream>>>(W_ih, W_hh, wcat);
        lstm_pipe<<<dim3(256), dim3(512), PART_BYTES, stream>>>(
            bias, wcat, xbf, hseq, out, flags);
    }
}

// Round 20
// 2892.258 us; speedup vs baseline: 4.5708x; 4.5708x over previous
//
#include <hip/hip_runtime.h>
#include <hip/hip_bf16.h>

using bf16x8 = __attribute__((ext_vector_type(8))) short;  // 8 bf16, 4 VGPRs
using f32x4  = __attribute__((ext_vector_type(4))) float;

static constexpr int NB = 64, NT = 256, NE = 1024, NH = 1024, NL = 3;
static constexpr int NR = 4096, KC = 2048;
static constexpr int STATE = NL * NB * NH;             // 196608
static constexpr int BH = NB * NH;                     // 65536 (one panel)
static constexpr size_t WCAT_E = (size_t)NL * NR * KC;  // 25,165,824 bf16
static constexpr size_t XBF_E  = (size_t)NT * NB * NE;  // 16,777,216 bf16
static constexpr size_t HSEQ_E = (size_t)(NT + 1) * STATE;  // 50,528,256 bf16
static constexpr int FSTR  = 32;                       // u32s per flag slot (128B)
static constexpr int NFLAG = 256 * FSTR;
static constexpr int NREL  = 32 * FSTR;
static constexpr size_t FLAGS_W = NFLAG + NREL;
static constexpr int PSTR = 18;                        // padded n-stride (2-way banks)
static constexpr size_t PART_BYTES = 3u * 8 * 4 * 16 * PSTR * 4;   // 110,592 B

// Fragment-tiled panel layout (64 m x 1024 k bf16 = 32x4 tiles of 1KB):
__host__ __device__ __forceinline__ size_t off_e(int m, int k) {
    return ((size_t)((m >> 4) * 32 + (k >> 5))) * 512 +
           (((k >> 3) & 3) * 16 + (m & 15)) * 8 + (k & 7);
}

// ---------------- prologue kernels ----------------

__global__ void __launch_bounds__(256)
convert_w(const float* __restrict__ wih, const float* __restrict__ whh,
          __hip_bfloat16* __restrict__ wcat) {
    size_t i = (size_t)blockIdx.x * 256 + threadIdx.x;
    const size_t stride = (size_t)gridDim.x * 256;
    for (; i < WCAT_E; i += stride) {
        const int e    = (int)(i & 7);
        const int lane = (int)((i >> 3) & 63);
        const int kt   = (int)((i >> 9) & 63);
        const int ug   = (int)((i >> 15) & 255);
        const int l    = (int)(i >> 23);
        const int nfr  = lane & 15, kg = lane >> 4;
        const int r    = (nfr >> 2) * 1024 + ug * 4 + (nfr & 3);
        const int k    = kt * 32 + kg * 8 + e;
        const float v = (k < NE) ? wih[((size_t)l * NR + r) * NE + k]
                                 : whh[((size_t)l * NR + r) * NH + (k - NE)];
        wcat[i] = __float2bfloat16(v);
    }
}

__global__ void __launch_bounds__(256)
convert_x(const float* __restrict__ x, __hip_bfloat16* __restrict__ xbf) {
    size_t i = (size_t)blockIdx.x * 256 + threadIdx.x;
    const size_t stride = (size_t)gridDim.x * 256;
    for (; i < XBF_E; i += stride) {
        const int e = (int)(i & (NE - 1));
        const int m = (int)((i >> 10) & 63);
        const int t = (int)(i >> 16);
        xbf[(size_t)t * BH + off_e(m, e)] =
            __float2bfloat16(x[((size_t)m * NT + t) * NE + e]);
    }
}

__global__ void __launch_bounds__(256)
init_h(const float* __restrict__ enc, __hip_bfloat16* __restrict__ h0,
       unsigned* __restrict__ flags) {
    const int i = blockIdx.x * 256 + threadIdx.x;
    if (i < STATE) {
        const int u = i & 1023, m = (i >> 10) & 63, l = i >> 16;
        h0[(size_t)l * BH + off_e(m, u)] = __float2bfloat16(enc[m * NH + u]);
    }
    if (i < (int)FLAGS_W) flags[i] = 0u;
}

// ---------------- helpers ----------------

__device__ __forceinline__ unsigned short bf16bits(float f) {
    const __hip_bfloat16 h = __float2bfloat16(f);
    union { __hip_bfloat16 h; unsigned short s; } u{h};
    return u.s;
}

// ---------------- root-poll barrier (~0.6us) ----------------
__device__ __forceinline__ void grid_barrier(unsigned* __restrict__ flags,
                                             unsigned* __restrict__ release,
                                             int bid, int tid, unsigned gen) {
    asm volatile("s_waitcnt vmcnt(0)" ::: "memory");
    __syncthreads();
    if (tid == 0)
        __hip_atomic_store(&flags[bid * FSTR], gen,
                           __ATOMIC_RELAXED, __HIP_MEMORY_SCOPE_AGENT);
    const int lane = tid & 63, w = tid >> 6;
    if (bid == 0) {
        if (tid < 256) {
            for (;;) {
                const unsigned v = __hip_atomic_load(&flags[tid * FSTR],
                                      __ATOMIC_RELAXED, __HIP_MEMORY_SCOPE_AGENT);
                if (__all((int)(v >= gen))) break;
                __builtin_amdgcn_s_sleep(2);
            }
        }
        __syncthreads();
        if (w < 4 && lane < 8)
            __hip_atomic_store(&release[(w * 8 + lane) * FSTR], gen,
                               __ATOMIC_RELAXED, __HIP_MEMORY_SCOPE_AGENT);
    } else {
        if (tid < 64) {
            for (;;) {
                const unsigned v = __hip_atomic_load(&release[(bid >> 3) * FSTR],
                                      __ATOMIC_RELAXED, __HIP_MEMORY_SCOPE_AGENT);
                if (v >= gen) break;
                __builtin_amdgcn_s_sleep(2);
            }
        }
        __syncthreads();
    }
}

#define LOAD8S(dst, base)                                         \
    _Pragma("unroll")                                             \
    for (int kb = 0; kb < 8; ++kb)                                \
        dst[kb] = *(const bf16x8*)((base) + kb * 512);

#define MFMA8(accv, asrc, bsrc)                                   \
    _Pragma("unroll")                                             \
    for (int kb = 0; kb < 8; ++kb)                                \
        accv = __builtin_amdgcn_mfma_f32_16x16x32_bf16(           \
            asrc[kb], bsrc[kb], accv, 0, 0, 0);

#define SB __builtin_amdgcn_sched_barrier(0)

#define ZEROACC                                                    \
    acc0 = f32x4{0.f, 0.f, 0.f, 0.f}; acc1 = f32x4{0.f, 0.f, 0.f, 0.f}; \
    acc2 = f32x4{0.f, 0.f, 0.f, 0.f}; acc3 = f32x4{0.f, 0.f, 0.f, 0.f};

// part index: [st][w][mt][m][n(PSTR=18 pad -> 2-way banks, free)]
__device__ __forceinline__ int pidx(int st, int w, int mt, int m, int n) {
    return (((st * 8 + w) * 4 + mt) * 16 + m) * PSTR + n;
}
#define STOREP(st)                                                 \
    _Pragma("unroll")                                              \
    for (int j = 0; j < 4; ++j) {                                  \
        part[pidx(st, wv, 0, mgrp + j, nfr)] = acc0[j];            \
        part[pidx(st, wv, 1, mgrp + j, nfr)] = acc1[j];            \
        part[pidx(st, wv, 2, mgrp + j, nfr)] = acc2[j];            \
        part[pidx(st, wv, 3, mgrp + j, nfr)] = acc3[j];            \
    }

// ---------------- fused 3-layer pipelined MFMA kernel --------------------
// Step s: l0(t=s) | l1(t=s-1) | l2(t=s-2). 5 rolling buffers (bA,bB,aX,aY,aZ)
// -> each load has >=2 MFMA clusters before its use. 258 flag barriers.
__global__ void __launch_bounds__(512, 2)
lstm_pipe(const float* __restrict__ bias,
          const __hip_bfloat16* __restrict__ wcat,
          const __hip_bfloat16* __restrict__ xbf,
          __hip_bfloat16* __restrict__ hseq,
          float* __restrict__ out,
          unsigned* __restrict__ flags)
{
    extern __shared__ float part[];
    const int tid  = threadIdx.x;
    const int lane = tid & 63;
    const int wv   = tid >> 6;            // 0..7: waves 0-3 x-part, 4-7 h-part
    const int bid  = blockIdx.x;
    const int ug   = (bid & 7) * 32 + (bid >> 3);   // XCD-swizzled unit group
    const int U0   = ug * 4;
    const int nfr  = lane & 15;
    const int mgrp = (lane >> 4) * 4;

    float* hT   = out;
    float* cT   = out + STATE;
    float* outs = out + 2 * STATE;
    unsigned* release = flags + NFLAG;

    const bool xpart = (wv < 4);
    const int  ksl   = xpart ? wv : (wv - 4);

    const __hip_bfloat16* wp0 = wcat + ((size_t)ug * 64 + wv * 8) * 512 + lane * 8;
    const __hip_bfloat16* wp1 = wp0 + (size_t)1 * NR * KC;
    const __hip_bfloat16* wp2 = wp0 + (size_t)2 * NR * KC;
    const size_t lane8 = (size_t)(ksl * 8) * 512 + lane * 8;

    float cA = 0.f, cB = 0.f;
    unsigned gen = 1;

    for (int s = 0; s < NT + 2; ++s) {
        const int t0 = (s < NT) ? s : NT - 1;
        const int t1c = (s - 1 < 0) ? 0 : ((s - 1 < NT) ? s - 1 : NT - 1);
        const int t2c = (s - 2 < 0) ? 0 : ((s - 2 < NT) ? s - 2 : NT - 1);

        const __hip_bfloat16* ap0 = xpart ? (xbf + (size_t)t0 * BH)
                                          : (hseq + (size_t)t0 * STATE);
        const __hip_bfloat16* ap1 = xpart ? (hseq + (size_t)(t1c + 1) * STATE)
                                          : (hseq + (size_t)t1c * STATE + BH);
        const __hip_bfloat16* ap2 = xpart ? (hseq + (size_t)(t2c + 1) * STATE + BH)
                                          : (hseq + (size_t)t2c * STATE + 2 * BH);
        const __hip_bfloat16* a00 = ap0 + lane8;            // mt stride 32*512
        const __hip_bfloat16* a10 = ap1 + lane8;
        const __hip_bfloat16* a20 = ap2 + lane8;

        bf16x8 bA[8], bB[8], aX[8], aY[8], aZ[8];
        f32x4 acc0, acc1, acc2, acc3;

        // ---- rolling 3-deep load/MFMA pipeline over 3 layers ----
        LOAD8S(bA, wp0);
        LOAD8S(aX, a00 + 0 * 32 * 512);
        LOAD8S(aY, a00 + 1 * 32 * 512);
        LOAD8S(aZ, a00 + 2 * 32 * 512);
        LOAD8S(bB, wp1);
        SB;
        ZEROACC;
        MFMA8(acc0, aX, bA); SB; LOAD8S(aX, a00 + 3 * 32 * 512); SB;
        MFMA8(acc1, aY, bA); SB; LOAD8S(aY, a10 + 0 * 32 * 512); SB;
        MFMA8(acc2, aZ, bA); SB; LOAD8S(aZ, a10 + 1 * 32 * 512); SB;
        MFMA8(acc3, aX, bA); SB; LOAD8S(aX, a10 + 2 * 32 * 512);
                                 LOAD8S(bA, wp2); SB;
        STOREP(0);
        ZEROACC;
        MFMA8(acc0, aY, bB); SB; LOAD8S(aY, a10 + 3 * 32 * 512); SB;
        MFMA8(acc1, aZ, bB); SB; LOAD8S(aZ, a20 + 0 * 32 * 512); SB;
        MFMA8(acc2, aX, bB); SB; LOAD8S(aX, a20 + 1 * 32 * 512); SB;
        MFMA8(acc3, aY, bB); SB; LOAD8S(aY, a20 + 2 * 32 * 512); SB;
        STOREP(1);
        ZEROACC;
        MFMA8(acc0, aZ, bA); SB; LOAD8S(aZ, a20 + 3 * 32 * 512); SB;
        MFMA8(acc1, aX, bA); SB;
        MFMA8(acc2, aY, bA); SB;
        MFMA8(acc3, aZ, bA); SB;
        STOREP(2);
        __syncthreads();

        // ---- cell phase: 384 threads, one layer each ----
        if (tid < 384) {
            const int st = tid >> 7, r = tid & 127;
            const int t  = s - st;
            if (t >= 0 && t < NT) {
                const int cm = r >> 1, cp = (r & 1) * 2;
                const float* bias_l = bias + (size_t)st * NR;
                float hn2[2], cn2[2];
                #pragma unroll
                for (int j = 0; j < 2; ++j) {
                    const int ul = cp + j;
                    const int cunit = U0 + ul;
                    float gv[4];
                    #pragma unroll
                    for (int g = 0; g < 4; ++g) {
                        float ssum = bias_l[g * NH + cunit];
                        #pragma unroll
                        for (int w2 = 0; w2 < 8; ++w2)
                            ssum += part[pidx(st, w2, cm >> 4, cm & 15, g * 4 + ul)];
                        gv[g] = ssum;
                    }
                    const float iv = 1.f / (1.f + __expf(-gv[0]));
                    const float fv = 1.f / (1.f + __expf(-gv[1]));
                    const float gg = 1.f - 2.f / (__expf(2.f * gv[2]) + 1.f);
                    const float ov = 1.f / (1.f + __expf(-gv[3]));
                    float& cref = (j == 0) ? cA : cB;
                    const float cn = fv * cref + iv * gg;
                    const float hn = ov * (1.f - 2.f / (__expf(2.f * cn) + 1.f));
                    cref = cn;
                    hn2[j] = hn; cn2[j] = cn;
                }
                __hip_bfloat16* hw = hseq + (size_t)(t + 1) * STATE + st * BH;
                const int u = U0 + cp;
                const size_t off = ((size_t)((cm >> 4) * 32 + (u >> 5))) * 512 +
                                   (((u >> 3) & 3) * 16 + (cm & 15)) * 8 + (u & 7);
                const unsigned pk = (unsigned)bf16bits(hn2[0]) |
                                    ((unsigned)bf16bits(hn2[1]) << 16);
                __hip_atomic_store((unsigned*)(hw + off), pk,
                                   __ATOMIC_RELAXED, __HIP_MEMORY_SCOPE_AGENT);
                if (st == 2) {
                    outs[((size_t)cm * NT + t) * NH + u]     = hn2[0];
                    outs[((size_t)cm * NT + t) * NH + u + 1] = hn2[1];
                }
                if (t == NT - 1) {
                    float* hT_l = hT + st * BH;
                    float* cT_l = cT + st * BH;
                    hT_l[cm * NH + u]     = hn2[0];
                    hT_l[cm * NH + u + 1] = hn2[1];
                    cT_l[cm * NH + u]     = cn2[0];
                    cT_l[cm * NH + u + 1] = cn2[1];
                }
            }
        }
        if (s < NT + 1) grid_barrier(flags, release, bid, tid, gen++);
    }
}

// ---------------- launcher ----------------

extern "C" void kernel_launch(void* const* d_in, const int* in_sizes, int n_in,
                              void* d_out, int out_size, void* d_ws, size_t ws_size,
                              hipStream_t stream) {
    const float* inputs = (const float*)d_in[0];
    const float* enc    = (const float*)d_in[1];
    const float* W_ih   = (const float*)d_in[2];
    const float* W_hh   = (const float*)d_in[3];
    const float* bias   = (const float*)d_in[4];
    float* out = (float*)d_out;

    __hip_bfloat16* wcat  = (__hip_bfloat16*)d_ws;
    __hip_bfloat16* xbf   = wcat + WCAT_E;
    __hip_bfloat16* hseq  = xbf + XBF_E;
    unsigned*       flags = (unsigned*)(hseq + HSEQ_E);
    // ws need ~185.0 MB: proven by R13-R18 passing runs.

    (void)hipFuncSetAttribute((const void*)lstm_pipe,
                              hipFuncAttributeMaxDynamicSharedMemorySize,
                              (int)PART_BYTES);

    convert_w<<<dim3(4096), dim3(256), 0, stream>>>(W_ih, W_hh, wcat);
    convert_x<<<dim3(2048), dim3(256), 0, stream>>>(inputs, xbf);
    init_h<<<dim3(768), dim3(256), 0, stream>>>(enc, hseq, flags);

    lstm_pipe<<<dim3(256), dim3(512), PART_BYTES, stream>>>(
        bias, wcat, xbf, hseq, out, flags);
}